// Round 1
// baseline (613.835 us; speedup 1.0000x reference)
//
#include <hip/hip_runtime.h>
#include <hip/hip_bf16.h>
#include <math.h>

#define CDIM 128
#define C4   32      // float4s per row
#define NCH  16      // nodes staged per chunk
#define CAP  1792    // max nodes whose scores fit in LDS (fallback: global ws)

__device__ __forceinline__ int lower_bound_i(const int* __restrict__ b, int n, int v) {
    int lo = 0, hi = n;
    while (lo < hi) { int mid = (lo + hi) >> 1; if (b[mid] < v) lo = mid + 1; else hi = mid; }
    return lo;
}

__global__ void seg_bounds_kernel(const int* __restrict__ batch, int N, int G,
                                  int* __restrict__ seg) {
    int g = blockIdx.x * blockDim.x + threadIdx.x;
    if (g < G) seg[g] = lower_bound_i(batch, N, g);
    if (g == 0) seg[G] = N;
}

// one block per graph; 256 threads = 32 channel-groups (4 ch each) x 8 node-groups (2 nodes each)
__launch_bounds__(256, 2)
__global__ void pool_kernel(const float* __restrict__ x,
                            const float* __restrict__ proj_w,
                            const float* __restrict__ proj_b,
                            const float* __restrict__ score_w,
                            const float* __restrict__ score_b,
                            const int* __restrict__ seg,
                            float* __restrict__ out,
                            float* __restrict__ s_ws,
                            int N) {
    // LDS: W 64KB + X 8KB + s 7KB + red/bc  => 81.4KB => 2 blocks/CU
    __shared__ float4 Ws[4096];        // swizzled: slot (c,u) holds W[c][u ^ ((c>>2)&7)]
    __shared__ float4 Xs[NCH * C4];    // natural [node][k4]
    __shared__ float  s_lds[CAP];
    __shared__ float  red[132];
    __shared__ float  bc[2];

    const int g = blockIdx.x;
    const int t = threadIdx.x;
    const int start = seg[g];
    const int cnt   = seg[g + 1] - start;

    if (cnt <= 0) {                    // empty graph: reference pools to zeros
        if (t < CDIM) out[g * CDIM + t] = 0.0f;
        return;
    }

    // ---- stage W (swizzled, coalesced: XOR permutes within 128B groups) ----
    const float4* Wg = (const float4*)proj_w;
    for (int s = t; s < 4096; s += 256) {
        int c = s >> 5, u = s & 31;
        Ws[s] = Wg[(c << 5) | (u ^ ((c >> 2) & 7))];
    }

    float* sbuf = (cnt <= CAP) ? s_lds : (s_ws + start);

    const int cg  = t & 31;            // channel group: channels cg*4 .. cg*4+3
    const int ng  = t >> 5;            // node group: local nodes ng*2, ng*2+1
    const int swz = cg & 7;            // = (c>>2)&7 for all 4 owned channels
    const int wbase = cg << 7;         // (cg*4) << 5
    const float4 bb = ((const float4*)proj_b)[cg];
    const float4 sw = ((const float4*)score_w)[cg];
    const float  sb = score_b[0];

    const float4* xg = (const float4*)x;

    // ================= phase 1: s[i] = score_w . tanh(W x_i + b) + score_b =================
    for (int cb = 0; cb < cnt; cb += NCH) {
        __syncthreads();               // previous chunk's readers done
        for (int s = t; s < NCH * C4; s += 256) {
            int nl = s >> 5, k4 = s & 31;
            int node = start + cb + nl;
            Xs[s] = (cb + nl < cnt && node < N) ? xg[node * C4 + k4]
                                                : make_float4(0.f, 0.f, 0.f, 0.f);
        }
        __syncthreads();

        float acc[4][2];
        #pragma unroll
        for (int i = 0; i < 4; ++i) { acc[i][0] = 0.f; acc[i][1] = 0.f; }

        const int nb0 = (ng << 1) << 5;        // Xs float4 base of node 0
        const int nb1 = nb0 + C4;              // node 1

        #pragma unroll 4
        for (int k4 = 0; k4 < C4; ++k4) {
            const int off = k4 ^ swz;
            const float4 xa = Xs[nb0 + k4];
            const float4 xb = Xs[nb1 + k4];
            #pragma unroll
            for (int i = 0; i < 4; ++i) {
                const float4 w = Ws[wbase + (i << 5) + off];
                acc[i][0] += w.x * xa.x + w.y * xa.y + w.z * xa.z + w.w * xa.w;
                acc[i][1] += w.x * xb.x + w.y * xb.y + w.z * xb.z + w.w * xb.w;
            }
        }

        // epilogue: bias + tanh + score dot, reduce over the 32 channel-group lanes
        float p[2];
        #pragma unroll
        for (int j = 0; j < 2; ++j) {
            p[j]  = sw.x * tanhf(acc[0][j] + bb.x);
            p[j] += sw.y * tanhf(acc[1][j] + bb.y);
            p[j] += sw.z * tanhf(acc[2][j] + bb.z);
            p[j] += sw.w * tanhf(acc[3][j] + bb.w);
            #pragma unroll
            for (int m = 1; m <= 16; m <<= 1) p[j] += __shfl_xor(p[j], m, 64);
        }
        if (cg == 0) {
            #pragma unroll
            for (int j = 0; j < 2; ++j) {
                int nl = cb + (ng << 1) + j;
                if (nl < cnt) sbuf[nl] = p[j] + sb;
            }
        }
    }
    __syncthreads();

    // ================= phase 2: segment softmax (max, then exp-sum; e stored in sbuf) =====
    float lm = -3.4e38f;
    for (int n = t; n < cnt; n += 256) lm = fmaxf(lm, sbuf[n]);
    #pragma unroll
    for (int m = 1; m < 64; m <<= 1) lm = fmaxf(lm, __shfl_xor(lm, m, 64));
    if ((t & 63) == 0) red[t >> 6] = lm;
    __syncthreads();
    if (t == 0) bc[0] = fmaxf(fmaxf(red[0], red[1]), fmaxf(red[2], red[3]));
    __syncthreads();
    const float mval = bc[0];

    float ls = 0.f;
    for (int n = t; n < cnt; n += 256) {
        float e = expf(sbuf[n] - mval);
        sbuf[n] = e;
        ls += e;
    }
    #pragma unroll
    for (int m = 1; m < 64; m <<= 1) ls += __shfl_xor(ls, m, 64);
    if ((t & 63) == 0) red[t >> 6] = ls;
    __syncthreads();
    if (t == 0) bc[1] = 1.0f / fmaxf(red[0] + red[1] + red[2] + red[3], 1e-30f);
    __syncthreads();
    const float inv = bc[1];

    // ================= phase 3: pooled[g][c] = sum_n w_n * x[n][c] ========================
    const int c = t & 127;
    const int h = t >> 7;
    float acc = 0.f;
    for (int n = h; n < cnt; n += 2)
        acc += sbuf[n] * x[(start + n) * CDIM + c];
    acc *= inv;
    if (h == 1) red[c] = acc;
    __syncthreads();
    if (h == 0) out[g * CDIM + c] = acc + red[c];
}

extern "C" void kernel_launch(void* const* d_in, const int* in_sizes, int n_in,
                              void* d_out, int out_size, void* d_ws, size_t ws_size,
                              hipStream_t stream) {
    const float* x       = (const float*)d_in[0];
    const float* proj_w  = (const float*)d_in[1];
    const float* proj_b  = (const float*)d_in[2];
    const float* score_w = (const float*)d_in[3];
    const float* score_b = (const float*)d_in[4];
    const int*   batch   = (const int*)d_in[5];

    const int N = in_sizes[0] / CDIM;
    const int G = out_size / CDIM;

    int*   seg  = (int*)d_ws;
    float* s_ws = (float*)((char*)d_ws + (((size_t)(G + 1) * 4 + 255) & ~(size_t)255));

    seg_bounds_kernel<<<(G + 255) / 256, 256, 0, stream>>>(batch, N, G, seg);
    pool_kernel<<<G, 256, 0, stream>>>(x, proj_w, proj_b, score_w, score_b,
                                       seg, (float*)d_out, s_ws, N);
}

// Round 2
// 377.717 us; speedup vs baseline: 1.6251x; 1.6251x over previous
//
#include <hip/hip_runtime.h>
#include <hip/hip_bf16.h>
#include <float.h>
#include <math.h>

#define CDIM 128

typedef __attribute__((ext_vector_type(8))) short short8v;   // 8 bf16 = 1 MFMA A/B frag
typedef __attribute__((ext_vector_type(4))) float f32x4;     // MFMA C/D frag

__device__ __forceinline__ short bf16b(float f) {
    __hip_bfloat16 h = __float2bfloat16(f);
    return __builtin_bit_cast(short, h);
}

// fast tanh via hardware exp: tanh(y) = 1 - 2/(exp(2y)+1)
__device__ __forceinline__ float tanh_fast(float y) {
    float e = __expf(2.0f * y);
    return 1.0f - 2.0f / (e + 1.0f);
}

__device__ __forceinline__ int lower_bound_i(const int* __restrict__ b, int n, int v) {
    int lo = 0, hi = n;
    while (lo < hi) { int mid = (lo + hi) >> 1; if (b[mid] < v) lo = mid + 1; else hi = mid; }
    return lo;
}

__global__ void seg_bounds_kernel(const int* __restrict__ batch, int N, int G,
                                  int* __restrict__ seg) {
    int g = blockIdx.x * blockDim.x + threadIdx.x;
    if (g < G) seg[g] = lower_bound_i(batch, N, g);
    if (g == 0) seg[G] = N;
}

// Pre-pack proj_w into bf16 MFMA B-fragments.
// Frag f = ct*4+ks, lane l: col c = ct*16+(l&15), k = ks*32+(l>>4)*8+j  (j=0..7)
// stored at wfrag[(f*64+l)*8 + j]
__global__ void wconv_kernel(const float* __restrict__ proj_w, short* __restrict__ wfrag) {
    int tid = blockIdx.x * 256 + threadIdx.x;       // 0..2047
    int f = tid >> 6, l = tid & 63;
    int c  = ((f >> 2) << 4) | (l & 15);
    int k0 = ((f & 3) << 5) | ((l >> 4) << 3);
    short8v v;
    #pragma unroll
    for (int j = 0; j < 8; ++j) v[j] = bf16b(proj_w[c * CDIM + k0 + j]);
    ((short8v*)wfrag)[tid] = v;
}

// One block (256 thr = 4 waves) per graph. Fused: MFMA scores + online softmax +
// fp32 pooling from the same LDS-staged x chunk. x read from HBM exactly once.
__launch_bounds__(256, 4)
__global__ void pool_kernel(const float* __restrict__ x,
                            const short* __restrict__ wfrag,
                            const float* __restrict__ proj_b,
                            const float* __restrict__ score_w,
                            const float* __restrict__ score_b,
                            const int* __restrict__ seg,
                            float* __restrict__ out,
                            int N) {
    // LDS: 32KB Xs + 256B cs + 4KB red + bc  = ~37KB -> 4 blocks/CU
    __shared__ float4 Xs[64 * 32];            // [row][slot], slot = f4 ^ (row&7)
    __shared__ float  cs[64];                 // chunk scores -> exp weights
    __shared__ __align__(16) float red[8 * 128];
    __shared__ float  bc[2];                  // {scale, chunk exp-sum}

    const int g = blockIdx.x;
    const int t = threadIdx.x;
    const int lane = t & 63;
    const int w = t >> 6;                     // wave id: row-tile w*16..w*16+15
    const int start = seg[g];
    const int cnt = seg[g + 1] - start;

    if (cnt <= 0) {                           // empty graph pools to zeros
        if (t < CDIM) out[g * CDIM + t] = 0.0f;
        return;
    }

    // W fragments: all 8 col-tiles x 4 k-steps in registers (128 VGPR)
    short8v wf[8][4];
    {
        const short8v* wfg = (const short8v*)wfrag;
        #pragma unroll
        for (int f = 0; f < 32; ++f) wf[f >> 2][f & 3] = wfg[(f << 6) | lane];
    }
    float swl[8], pbl[8];
    #pragma unroll
    for (int ct = 0; ct < 8; ++ct) {
        swl[ct] = score_w[(ct << 4) + (lane & 15)];
        pbl[ct] = proj_b[(ct << 4) + (lane & 15)];
    }
    const float sb = score_b[0];

    const float4* __restrict__ x4 = (const float4*)x;
    const int g8 = t >> 5;                    // pooling: node stride-8 group
    const int c4 = t & 31;                    // pooling: float4 column slot

    float m_run = -FLT_MAX, l_run = 0.0f;
    float4 pa = make_float4(0.f, 0.f, 0.f, 0.f);

    for (int cb = 0; cb < cnt; cb += 64) {
        const int chunk_n = min(64, cnt - cb);
        __syncthreads();                      // Xs/cs free to overwrite

        // ---- stage 64 rows (fp32, swizzled) ----
        #pragma unroll
        for (int i = 0; i < 8; ++i) {
            int q = t + (i << 8);
            int row = q >> 5, f4 = q & 31;
            size_t gr = (size_t)min(start + cb + row, N - 1);  // clamp (pads unused)
            Xs[(row << 5) | (f4 ^ (row & 7))] = x4[gr * 32 + f4];
        }
        __syncthreads();

        // ---- MFMA: wave w computes scores of rows w*16..w*16+15 ----
        f32x4 acc[8];
        #pragma unroll
        for (int ct = 0; ct < 8; ++ct) acc[ct] = (f32x4){0.f, 0.f, 0.f, 0.f};

        const int arow = (w << 4) | (lane & 15);
        #pragma unroll
        for (int ks = 0; ks < 4; ++ks) {
            int f4a = (ks << 3) | ((lane >> 4) << 1);
            float4 a0 = Xs[(arow << 5) | (f4a ^ (arow & 7))];
            float4 a1 = Xs[(arow << 5) | ((f4a + 1) ^ (arow & 7))];
            short8v af;
            af[0] = bf16b(a0.x); af[1] = bf16b(a0.y); af[2] = bf16b(a0.z); af[3] = bf16b(a0.w);
            af[4] = bf16b(a1.x); af[5] = bf16b(a1.y); af[6] = bf16b(a1.z); af[7] = bf16b(a1.w);
            #pragma unroll
            for (int ct = 0; ct < 8; ++ct)
                acc[ct] = __builtin_amdgcn_mfma_f32_16x16x32_bf16(af, wf[ct][ks], acc[ct], 0, 0, 0);
        }

        // ---- epilogue: s = sum_c sw[c]*tanh(h+b) ; reduce over 16 col-lanes ----
        #pragma unroll
        for (int r = 0; r < 4; ++r) {
            float s = 0.f;
            #pragma unroll
            for (int ct = 0; ct < 8; ++ct)
                s += swl[ct] * tanh_fast(acc[ct][r] + pbl[ct]);
            s += __shfl_xor(s, 1); s += __shfl_xor(s, 2);
            s += __shfl_xor(s, 4); s += __shfl_xor(s, 8);
            if ((lane & 15) == 0)
                cs[(w << 4) | ((lane >> 4) << 2) | r] = s + sb;
        }
        __syncthreads();

        // ---- online softmax update (wave 0 only) ----
        if (t < 64) {
            float v = (t < chunk_n) ? cs[t] : -FLT_MAX;
            float mx = v;
            mx = fmaxf(mx, __shfl_xor(mx, 1));  mx = fmaxf(mx, __shfl_xor(mx, 2));
            mx = fmaxf(mx, __shfl_xor(mx, 4));  mx = fmaxf(mx, __shfl_xor(mx, 8));
            mx = fmaxf(mx, __shfl_xor(mx, 16)); mx = fmaxf(mx, __shfl_xor(mx, 32));
            float m_new = fmaxf(m_run, mx);
            float sc = __expf(m_run - m_new);           // first chunk: exp(-huge)=0
            float e = (t < chunk_n) ? __expf(v - m_new) : 0.f;
            float ssum = e;
            ssum += __shfl_xor(ssum, 1);  ssum += __shfl_xor(ssum, 2);
            ssum += __shfl_xor(ssum, 4);  ssum += __shfl_xor(ssum, 8);
            ssum += __shfl_xor(ssum, 16); ssum += __shfl_xor(ssum, 32);
            cs[t] = e;
            if (t == 0) { bc[0] = sc; bc[1] = ssum; }
            m_run = m_new;
        }
        __syncthreads();

        // ---- rescale + pooling accumulate (fp32 from LDS) ----
        const float sc = bc[0];
        l_run = l_run * sc + bc[1];
        pa.x *= sc; pa.y *= sc; pa.z *= sc; pa.w *= sc;

        #pragma unroll
        for (int i = 0; i < 8; ++i) {
            int n = (i << 3) | g8;
            float e = cs[n];                          // 0 for pad rows
            float4 xv = Xs[(n << 5) | (c4 ^ (n & 7))];
            pa.x += e * xv.x; pa.y += e * xv.y; pa.z += e * xv.z; pa.w += e * xv.w;
        }
    }

    // ---- cross-group reduce + normalize ----
    *(float4*)&red[(g8 << 7) + (c4 << 2)] = pa;
    __syncthreads();
    if (t < CDIM) {
        float v = 0.f;
        #pragma unroll
        for (int j = 0; j < 8; ++j) v += red[j * CDIM + t];
        out[g * CDIM + t] = v * (1.0f / fmaxf(l_run, 1e-30f));
    }
}

extern "C" void kernel_launch(void* const* d_in, const int* in_sizes, int n_in,
                              void* d_out, int out_size, void* d_ws, size_t ws_size,
                              hipStream_t stream) {
    const float* x       = (const float*)d_in[0];
    const float* proj_w  = (const float*)d_in[1];
    const float* proj_b  = (const float*)d_in[2];
    const float* score_w = (const float*)d_in[3];
    const float* score_b = (const float*)d_in[4];
    const int*   batch   = (const int*)d_in[5];

    const int N = in_sizes[0] / CDIM;
    const int G = out_size / CDIM;

    int*   seg   = (int*)d_ws;
    short* wfrag = (short*)((char*)d_ws + (((size_t)(G + 1) * 4 + 255) & ~(size_t)255));

    seg_bounds_kernel<<<(G + 255) / 256, 256, 0, stream>>>(batch, N, G, seg);
    wconv_kernel<<<8, 256, 0, stream>>>(proj_w, wfrag);
    pool_kernel<<<G, 256, 0, stream>>>(x, wfrag, proj_b, score_w, score_b,
                                       seg, (float*)d_out, N);
}

// Round 3
// 136.299 us; speedup vs baseline: 4.5036x; 2.7712x over previous
//
#include <hip/hip_runtime.h>
#include <hip/hip_bf16.h>
#include <float.h>
#include <math.h>

#define CDIM 128

typedef __attribute__((ext_vector_type(8))) short short8v;   // 8 bf16 = 1 MFMA A/B frag
typedef __attribute__((ext_vector_type(4))) float f32x4;     // MFMA C/D frag

__device__ __forceinline__ short bf16b(float f) {
    __hip_bfloat16 h = __float2bfloat16(f);
    return __builtin_bit_cast(short, h);
}

// fast tanh via hardware exp: tanh(y) = 1 - 2/(exp(2y)+1)
__device__ __forceinline__ float tanh_fast(float y) {
    float e = __expf(2.0f * y);
    return 1.0f - 2.0f / (e + 1.0f);
}

__device__ __forceinline__ int lower_bound_i(const int* __restrict__ b, int n, int v) {
    int lo = 0, hi = n;
    while (lo < hi) { int mid = (lo + hi) >> 1; if (b[mid] < v) lo = mid + 1; else hi = mid; }
    return lo;
}

__global__ void seg_bounds_kernel(const int* __restrict__ batch, int N, int G,
                                  int* __restrict__ seg) {
    int g = blockIdx.x * blockDim.x + threadIdx.x;
    if (g < G) seg[g] = lower_bound_i(batch, N, g);
    if (g == 0) seg[G] = N;
}

// Pre-pack proj_w into bf16 MFMA B-fragments.
// Frag f = ct*4+ks, lane l: col c = ct*16+(l&15), k = ks*32+(l>>4)*8+j  (j=0..7)
__global__ void wconv_kernel(const float* __restrict__ proj_w, short* __restrict__ wfrag) {
    int tid = blockIdx.x * 256 + threadIdx.x;       // 0..2047
    int f = tid >> 6, l = tid & 63;
    int c  = ((f >> 2) << 4) | (l & 15);
    int k0 = ((f & 3) << 5) | ((l >> 4) << 3);
    short8v v;
    #pragma unroll
    for (int j = 0; j < 8; ++j) v[j] = bf16b(proj_w[c * CDIM + k0 + j]);
    ((short8v*)wfrag)[tid] = v;
}

// One block (256 thr = 4 waves) per graph. Wave w owns column-tiles {2w, 2w+1}
// (W frags = 32 VGPR) and computes all 64 rows of the chunk (acc = 32 VGPR).
// Fused: MFMA scores + cross-wave score reduce + online softmax + fp32 pooling
// from the same LDS-staged x chunk. x read from HBM exactly once. No spills.
__launch_bounds__(256, 4)
__global__ void pool_kernel(const float* __restrict__ x,
                            const short* __restrict__ wfrag,
                            const float* __restrict__ proj_b,
                            const float* __restrict__ score_w,
                            const float* __restrict__ score_b,
                            const int* __restrict__ seg,
                            float* __restrict__ out,
                            int N) {
    // LDS: 32KB Xs + 1KB ps + 256B cs + 4KB red + bc  = ~38.3KB -> 4 blocks/CU
    __shared__ float4 Xs[64 * 32];            // [row][slot], slot = f4 ^ (row&7)
    __shared__ float  ps[4 * 64];             // per-wave score partials
    __shared__ float  cs[64];                 // chunk scores -> exp weights
    __shared__ __align__(16) float red[8 * 128];
    __shared__ float  bc[2];                  // {scale, chunk exp-sum}

    const int g = blockIdx.x;
    const int t = threadIdx.x;
    const int lane = t & 63;
    const int w = t >> 6;                     // wave id: owns col-tiles 2w, 2w+1
    const int start = seg[g];
    const int cnt = seg[g + 1] - start;

    if (cnt <= 0) {                           // empty graph pools to zeros
        if (t < CDIM) out[g * CDIM + t] = 0.0f;
        return;
    }

    // W fragments for this wave's 2 column-tiles: 8 frags = 32 VGPR
    short8v wf[2][4];
    {
        const short8v* wfg = (const short8v*)wfrag;
        #pragma unroll
        for (int j = 0; j < 2; ++j)
            #pragma unroll
            for (int ks = 0; ks < 4; ++ks)
                wf[j][ks] = wfg[((((w << 1) | j) << 2 | ks) << 6) | lane];
    }
    float swl[2], pbl[2];
    #pragma unroll
    for (int j = 0; j < 2; ++j) {
        swl[j] = score_w[(((w << 1) | j) << 4) + (lane & 15)];
        pbl[j] = proj_b[(((w << 1) | j) << 4) + (lane & 15)];
    }
    const float sb = score_b[0];

    const float4* __restrict__ x4 = (const float4*)x;
    const int g8 = t >> 5;                    // pooling: node stride-8 group
    const int c4 = t & 31;                    // pooling: float4 column slot

    float m_run = -FLT_MAX, l_run = 0.0f;
    float4 pa = make_float4(0.f, 0.f, 0.f, 0.f);

    for (int cb = 0; cb < cnt; cb += 64) {
        const int chunk_n = min(64, cnt - cb);
        __syncthreads();                      // Xs/cs free to overwrite

        // ---- stage 64 rows (fp32, swizzled, coalesced) ----
        #pragma unroll
        for (int i = 0; i < 8; ++i) {
            int q = t + (i << 8);
            int row = q >> 5, f4 = q & 31;
            size_t gr = (size_t)min(start + cb + row, N - 1);  // clamp (pads unused)
            Xs[(row << 5) | (f4 ^ (row & 7))] = x4[gr * 32 + f4];
        }
        __syncthreads();

        // ---- MFMA: all 4 row-tiles x this wave's 2 col-tiles ----
        f32x4 acc[4][2];
        #pragma unroll
        for (int rt = 0; rt < 4; ++rt) {
            acc[rt][0] = (f32x4){0.f, 0.f, 0.f, 0.f};
            acc[rt][1] = (f32x4){0.f, 0.f, 0.f, 0.f};
        }
        #pragma unroll
        for (int rt = 0; rt < 4; ++rt) {
            const int arow = (rt << 4) | (lane & 15);
            #pragma unroll
            for (int ks = 0; ks < 4; ++ks) {
                int f4a = (ks << 3) | ((lane >> 4) << 1);
                float4 a0 = Xs[(arow << 5) | (f4a ^ (arow & 7))];
                float4 a1 = Xs[(arow << 5) | ((f4a + 1) ^ (arow & 7))];
                short8v af;
                af[0] = bf16b(a0.x); af[1] = bf16b(a0.y); af[2] = bf16b(a0.z); af[3] = bf16b(a0.w);
                af[4] = bf16b(a1.x); af[5] = bf16b(a1.y); af[6] = bf16b(a1.z); af[7] = bf16b(a1.w);
                acc[rt][0] = __builtin_amdgcn_mfma_f32_16x16x32_bf16(af, wf[0][ks], acc[rt][0], 0, 0, 0);
                acc[rt][1] = __builtin_amdgcn_mfma_f32_16x16x32_bf16(af, wf[1][ks], acc[rt][1], 0, 0, 0);
            }
        }

        // ---- epilogue: partial s over this wave's 32 channels, per row ----
        #pragma unroll
        for (int rt = 0; rt < 4; ++rt) {
            #pragma unroll
            for (int r = 0; r < 4; ++r) {
                float s = swl[0] * tanh_fast(acc[rt][0][r] + pbl[0])
                        + swl[1] * tanh_fast(acc[rt][1][r] + pbl[1]);
                s += __shfl_xor(s, 1); s += __shfl_xor(s, 2);
                s += __shfl_xor(s, 4); s += __shfl_xor(s, 8);
                if ((lane & 15) == 0)
                    ps[(w << 6) | (rt << 4) | ((lane >> 4) << 2) | r] = s;
            }
        }
        __syncthreads();

        // ---- online softmax update (wave 0 only) ----
        if (t < 64) {
            float v = (t < chunk_n)
                    ? (ps[t] + ps[64 + t] + ps[128 + t] + ps[192 + t] + sb)
                    : -FLT_MAX;
            float mx = v;
            mx = fmaxf(mx, __shfl_xor(mx, 1));  mx = fmaxf(mx, __shfl_xor(mx, 2));
            mx = fmaxf(mx, __shfl_xor(mx, 4));  mx = fmaxf(mx, __shfl_xor(mx, 8));
            mx = fmaxf(mx, __shfl_xor(mx, 16)); mx = fmaxf(mx, __shfl_xor(mx, 32));
            float m_new = fmaxf(m_run, mx);
            float sc = __expf(m_run - m_new);           // first chunk: exp(-huge)=0
            float e = (t < chunk_n) ? __expf(v - m_new) : 0.f;
            float ssum = e;
            ssum += __shfl_xor(ssum, 1);  ssum += __shfl_xor(ssum, 2);
            ssum += __shfl_xor(ssum, 4);  ssum += __shfl_xor(ssum, 8);
            ssum += __shfl_xor(ssum, 16); ssum += __shfl_xor(ssum, 32);
            cs[t] = e;
            if (t == 0) { bc[0] = sc; bc[1] = ssum; }
            m_run = m_new;
        }
        __syncthreads();

        // ---- rescale + pooling accumulate (fp32 from LDS) ----
        const float sc = bc[0];
        l_run = l_run * sc + bc[1];
        pa.x *= sc; pa.y *= sc; pa.z *= sc; pa.w *= sc;

        #pragma unroll
        for (int i = 0; i < 8; ++i) {
            int n = (i << 3) | g8;
            float e = cs[n];                          // 0 for pad rows
            float4 xv = Xs[(n << 5) | (c4 ^ (n & 7))];
            pa.x += e * xv.x; pa.y += e * xv.y; pa.z += e * xv.z; pa.w += e * xv.w;
        }
    }

    // ---- cross-group reduce + normalize ----
    *(float4*)&red[(g8 << 7) + (c4 << 2)] = pa;
    __syncthreads();
    if (t < CDIM) {
        float v = 0.f;
        #pragma unroll
        for (int j = 0; j < 8; ++j) v += red[j * CDIM + t];
        out[g * CDIM + t] = v * (1.0f / fmaxf(l_run, 1e-30f));
    }
}

extern "C" void kernel_launch(void* const* d_in, const int* in_sizes, int n_in,
                              void* d_out, int out_size, void* d_ws, size_t ws_size,
                              hipStream_t stream) {
    const float* x       = (const float*)d_in[0];
    const float* proj_w  = (const float*)d_in[1];
    const float* proj_b  = (const float*)d_in[2];
    const float* score_w = (const float*)d_in[3];
    const float* score_b = (const float*)d_in[4];
    const int*   batch   = (const int*)d_in[5];

    const int N = in_sizes[0] / CDIM;
    const int G = out_size / CDIM;

    int*   seg   = (int*)d_ws;
    short* wfrag = (short*)((char*)d_ws + (((size_t)(G + 1) * 4 + 255) & ~(size_t)255));

    seg_bounds_kernel<<<(G + 255) / 256, 256, 0, stream>>>(batch, N, G, seg);
    wconv_kernel<<<8, 256, 0, stream>>>(proj_w, wfrag);
    pool_kernel<<<G, 256, 0, stream>>>(x, wfrag, proj_b, score_w, score_b,
                                       seg, (float*)d_out, N);
}

// Round 4
// 94.644 us; speedup vs baseline: 6.4857x; 1.4401x over previous
//
#include <hip/hip_runtime.h>
#include <hip/hip_bf16.h>
#include <float.h>
#include <math.h>

#define CDIM 128

typedef __attribute__((ext_vector_type(8))) short short8v;   // 8 bf16 = 1 MFMA A/B frag
typedef __attribute__((ext_vector_type(4))) short short4v;   // 4 bf16 (8B LDS store)
typedef __attribute__((ext_vector_type(4))) float f32x4;     // MFMA C/D frag

__device__ __forceinline__ short bf16b(float f) {
    __hip_bfloat16 h = __float2bfloat16(f);
    return __builtin_bit_cast(short, h);
}

// fast tanh via hardware exp: tanh(y) = 1 - 2/(exp(2y)+1)
__device__ __forceinline__ float tanh_fast(float y) {
    float e = __expf(2.0f * y);
    return 1.0f - 2.0f / (e + 1.0f);
}

__device__ __forceinline__ int lower_bound_i(const int* __restrict__ b, int n, int v) {
    int lo = 0, hi = n;
    while (lo < hi) { int mid = (lo + hi) >> 1; if (b[mid] < v) lo = mid + 1; else hi = mid; }
    return lo;
}

__global__ void seg_bounds_kernel(const int* __restrict__ batch, int N, int G,
                                  int* __restrict__ seg) {
    int g = blockIdx.x * blockDim.x + threadIdx.x;
    if (g < G) seg[g] = lower_bound_i(batch, N, g);
    if (g == 0) seg[G] = N;
}

// Pre-pack proj_w into bf16 MFMA B-fragments.
// Frag f = ct*4+ks, lane l: col c = ct*16+(l&15), k = ks*32+(l>>4)*8+j  (j=0..7)
__global__ void wconv_kernel(const float* __restrict__ proj_w, short* __restrict__ wfrag) {
    int tid = blockIdx.x * 256 + threadIdx.x;       // 0..2047
    int f = tid >> 6, l = tid & 63;
    int c  = ((f >> 2) << 4) | (l & 15);
    int k0 = ((f & 3) << 5) | ((l >> 4) << 3);
    short8v v;
    #pragma unroll
    for (int j = 0; j < 8; ++j) v[j] = bf16b(proj_w[c * CDIM + k0 + j]);
    ((short8v*)wfrag)[tid] = v;
}

// One block (256 thr = 4 waves) per graph. Wave w owns column-tiles {2w, 2w+1}.
// Staging converts x->bf16 ONCE into swizzled LDS (MFMA A side); the fp32
// float4s stay in registers and pooling runs register-only (thread mapping for
// stage and pool is identical). x read from HBM exactly once. 3 barriers/chunk.
__launch_bounds__(256, 4)
__global__ void pool_kernel(const float* __restrict__ x,
                            const short* __restrict__ wfrag,
                            const float* __restrict__ proj_b,
                            const float* __restrict__ score_w,
                            const float* __restrict__ score_b,
                            const int* __restrict__ seg,
                            float* __restrict__ out,
                            int N) {
    // LDS: 16KB XsB + 1KB ps + 256B cs + 4KB red + bc = ~21.3KB
    __shared__ short XsB[64 * 128];           // bf16, short idx: row*128 + (k ^ ((row&7)<<3))
    __shared__ float ps[4 * 64];              // per-wave score partials
    __shared__ float cs[64];                  // chunk scores -> exp weights
    __shared__ __align__(16) float red[8 * 128];
    __shared__ float bc[2];                   // {scale, chunk exp-sum}

    const int g = blockIdx.x;
    const int t = threadIdx.x;
    const int lane = t & 63;
    const int w = t >> 6;                     // wave id: owns col-tiles 2w, 2w+1
    const int start = seg[g];
    const int cnt = seg[g + 1] - start;

    if (cnt <= 0) {                           // empty graph pools to zeros
        if (t < CDIM) out[g * CDIM + t] = 0.0f;
        return;
    }

    // W fragments for this wave's 2 column-tiles: 8 frags = 32 VGPR
    short8v wf[2][4];
    {
        const short8v* wfg = (const short8v*)wfrag;
        #pragma unroll
        for (int j = 0; j < 2; ++j)
            #pragma unroll
            for (int ks = 0; ks < 4; ++ks)
                wf[j][ks] = wfg[((((w << 1) | j) << 2 | ks) << 6) | lane];
    }
    float swl[2], pbl[2];
    #pragma unroll
    for (int j = 0; j < 2; ++j) {
        swl[j] = score_w[(((w << 1) | j) << 4) + (lane & 15)];
        pbl[j] = proj_b[(((w << 1) | j) << 4) + (lane & 15)];
    }
    const float sb = score_b[0];

    const float4* __restrict__ x4 = (const float4*)x;
    const int g8 = t >> 5;                    // stage/pool row phase (0..7)
    const int c4 = t & 31;                    // float4 column slot
    const int al = lane & 15, ah = lane >> 4;

    float m_run = -FLT_MAX, l_run = 0.0f;
    float4 pa = make_float4(0.f, 0.f, 0.f, 0.f);

    for (int cb = 0; cb < cnt; cb += 64) {
        const int chunk_n = min(64, cnt - cb);

        // ---- stage: global -> fp32 regs + bf16 swizzled LDS (converted ONCE) ----
        float4 xr[8];
        #pragma unroll
        for (int i = 0; i < 8; ++i) {
            int row = g8 + (i << 3);
            size_t gr = (size_t)min(start + cb + row, N - 1);   // clamp (pads zeroed later)
            xr[i] = x4[gr * 32 + c4];
        }
        #pragma unroll
        for (int i = 0; i < 8; ++i) {
            int row = g8 + (i << 3);
            short4v b;
            b[0] = bf16b(xr[i].x); b[1] = bf16b(xr[i].y);
            b[2] = bf16b(xr[i].z); b[3] = bf16b(xr[i].w);
            *(short4v*)&XsB[(row << 7) | ((c4 << 2) ^ ((row & 7) << 3))] = b;
        }
        __syncthreads();                      // sync1: XsB ready

        // ---- per row-tile: 8 MFMA + tanh/score epilogue (acc live = 8 VGPR) ----
        #pragma unroll
        for (int rt = 0; rt < 4; ++rt) {
            const int arow = (rt << 4) | al;
            const int rsw = (arow & 7) << 3;
            f32x4 a0 = (f32x4){0.f, 0.f, 0.f, 0.f};
            f32x4 a1 = (f32x4){0.f, 0.f, 0.f, 0.f};
            #pragma unroll
            for (int ks = 0; ks < 4; ++ks) {
                short8v af = *(const short8v*)&XsB[(arow << 7) | (((ks << 5) | (ah << 3)) ^ rsw)];
                a0 = __builtin_amdgcn_mfma_f32_16x16x32_bf16(af, wf[0][ks], a0, 0, 0, 0);
                a1 = __builtin_amdgcn_mfma_f32_16x16x32_bf16(af, wf[1][ks], a1, 0, 0, 0);
            }
            #pragma unroll
            for (int r = 0; r < 4; ++r) {
                float s = swl[0] * tanh_fast(a0[r] + pbl[0])
                        + swl[1] * tanh_fast(a1[r] + pbl[1]);
                s += __shfl_xor(s, 1); s += __shfl_xor(s, 2);
                s += __shfl_xor(s, 4); s += __shfl_xor(s, 8);
                if (al == 0) ps[(w << 6) | (rt << 4) | (ah << 2) | r] = s;
            }
        }
        __syncthreads();                      // sync2: ps complete, XsB reads done

        // ---- online softmax update (wave 0) ----
        if (t < 64) {
            float v = (t < chunk_n)
                    ? (ps[t] + ps[64 + t] + ps[128 + t] + ps[192 + t] + sb)
                    : -FLT_MAX;
            float mx = v;
            mx = fmaxf(mx, __shfl_xor(mx, 1));  mx = fmaxf(mx, __shfl_xor(mx, 2));
            mx = fmaxf(mx, __shfl_xor(mx, 4));  mx = fmaxf(mx, __shfl_xor(mx, 8));
            mx = fmaxf(mx, __shfl_xor(mx, 16)); mx = fmaxf(mx, __shfl_xor(mx, 32));
            float m_new = fmaxf(m_run, mx);
            float sc = __expf(m_run - m_new);           // first chunk: exp(-huge)=0
            float e = (t < chunk_n) ? __expf(v - m_new) : 0.f;
            float ssum = e;
            ssum += __shfl_xor(ssum, 1);  ssum += __shfl_xor(ssum, 2);
            ssum += __shfl_xor(ssum, 4);  ssum += __shfl_xor(ssum, 8);
            ssum += __shfl_xor(ssum, 16); ssum += __shfl_xor(ssum, 32);
            cs[t] = e;
            if (t == 0) { bc[0] = sc; bc[1] = ssum; }
            m_run = m_new;
        }
        __syncthreads();                      // sync3: cs/bc ready

        // ---- rescale + pooling accumulate (registers + cs broadcast) ----
        const float sc = bc[0];
        l_run = l_run * sc + bc[1];
        pa.x *= sc; pa.y *= sc; pa.z *= sc; pa.w *= sc;
        #pragma unroll
        for (int i = 0; i < 8; ++i) {
            float e = cs[g8 + (i << 3)];              // 0 for pad rows; broadcast read
            pa.x += e * xr[i].x; pa.y += e * xr[i].y;
            pa.z += e * xr[i].z; pa.w += e * xr[i].w;
        }
    }

    // ---- cross-group reduce + normalize ----
    *(float4*)&red[(g8 << 7) + (c4 << 2)] = pa;
    __syncthreads();
    if (t < CDIM) {
        float v = 0.f;
        #pragma unroll
        for (int j = 0; j < 8; ++j) v += red[j * CDIM + t];
        out[g * CDIM + t] = v * (1.0f / fmaxf(l_run, 1e-30f));
    }
}

extern "C" void kernel_launch(void* const* d_in, const int* in_sizes, int n_in,
                              void* d_out, int out_size, void* d_ws, size_t ws_size,
                              hipStream_t stream) {
    const float* x       = (const float*)d_in[0];
    const float* proj_w  = (const float*)d_in[1];
    const float* proj_b  = (const float*)d_in[2];
    const float* score_w = (const float*)d_in[3];
    const float* score_b = (const float*)d_in[4];
    const int*   batch   = (const int*)d_in[5];

    const int N = in_sizes[0] / CDIM;
    const int G = out_size / CDIM;

    int*   seg   = (int*)d_ws;
    short* wfrag = (short*)((char*)d_ws + (((size_t)(G + 1) * 4 + 255) & ~(size_t)255));

    seg_bounds_kernel<<<(G + 255) / 256, 256, 0, stream>>>(batch, N, G, seg);
    wconv_kernel<<<8, 256, 0, stream>>>(proj_w, wfrag);
    pool_kernel<<<G, 256, 0, stream>>>(x, wfrag, proj_b, score_w, score_b,
                                       seg, (float*)d_out, N);
}